// Round 15
// baseline (261.123 us; speedup 1.0000x reference)
//
#include <hip/hip_runtime.h>

#define N_NODES 100000
#define N_HE    20000
#define N_EDGE  800000
#define DIM     128
#define NBS     98        // src buckets of 1024 nodes
#define NBD     40        // dst buckets of 512 hyperedges
#define CAP_S   9600
#define CAP_D   22500
#define SUBS    8
#define SUBD    16
#define PB      256       // bin blocks per frame
#define CHUNK   3125      // 256*3125 = 800000 exact
#define STB     400       // stats/logits blocks per frame/job
#define GPB     512       // gpass blocks per frame
#define GGRP    32

struct P {
  const void* x[2]; const void* ea[2]; const int* ei[2];
  const void* gw[2]; const void* gb[2]; const void* gms[2];
  const void* W[2]; const void* att[2]; const void* bias[2];
  float *stats, *a, *cw, *v, *u, *cst, *sPart, *wnPart, *gpart, *gpart2;
  unsigned *curS, *curD, *done, *recS, *recD;
  unsigned short *lnb, *lhb, *hsv;
  int* flag; void* out;
};

// ---- helpers ----
typedef float __attribute__((ext_vector_type(4))) f4v;
__device__ __forceinline__ float4 ldnt(const float4* p){
  f4v v = __builtin_nontemporal_load((const f4v*)p);
  return make_float4(v.x, v.y, v.z, v.w);
}
__device__ __forceinline__ float ldf(const void* p, int i, int isbf){
  if (isbf){ unsigned short h = ((const unsigned short*)p)[i]; return __uint_as_float(((unsigned)h)<<16); }
  return ((const float*)p)[i];
}
__device__ __forceinline__ float b2f(unsigned short h){
  return __uint_as_float(((unsigned)h)<<16);
}
struct F8 { float v[8]; };
__device__ __forceinline__ F8 load8(const void* p, long idx, int isbf){
  F8 r;
  if (isbf){
    uint4 q = *(const uint4*)((const unsigned short*)p + idx);
    r.v[0]=__uint_as_float(q.x<<16); r.v[1]=__uint_as_float(q.x&0xFFFF0000u);
    r.v[2]=__uint_as_float(q.y<<16); r.v[3]=__uint_as_float(q.y&0xFFFF0000u);
    r.v[4]=__uint_as_float(q.z<<16); r.v[5]=__uint_as_float(q.z&0xFFFF0000u);
    r.v[6]=__uint_as_float(q.w<<16); r.v[7]=__uint_as_float(q.w&0xFFFF0000u);
  } else {
    const float4* q = (const float4*)((const float*)p + idx);
    float4 A=q[0], B=q[1];
    r.v[0]=A.x;r.v[1]=A.y;r.v[2]=A.z;r.v[3]=A.w;
    r.v[4]=B.x;r.v[5]=B.y;r.v[6]=B.z;r.v[7]=B.w;
  }
  return r;
}
__device__ __forceinline__ F8 load8nt(const void* p, long idx, int isbf){
  F8 r;
  if (isbf){
    return load8(p, idx, 1);
  } else {
    const float4* q = (const float4*)((const float*)p + idx);
    float4 A=ldnt(q), B=ldnt(q+1);
    r.v[0]=A.x;r.v[1]=A.y;r.v[2]=A.z;r.v[3]=A.w;
    r.v[4]=B.x;r.v[5]=B.y;r.v[6]=B.z;r.v[7]=B.w;
  }
  return r;
}
__device__ __forceinline__ unsigned short f2bf(float f){
  unsigned u = __float_as_uint(f);
  return (unsigned short)((u + 0x7FFFu + ((u>>16)&1u)) >> 16);   // RNE
}

// ---- dtype detection + zero stats/flag/cursors/done ----
__global__ void k_detect(P p){
  for (int i=threadIdx.x; i<880; i+=256) p.stats[i]=0.f;
  const unsigned* w = (const unsigned*)p.x[0];
  int bad = 0;
  for (int i = threadIdx.x; i < 4096; i += 256){
    float g = __uint_as_float(w[i]<<16);
    float ag = fabsf(g);
    if (!(ag==0.0f || (ag>1e-8f && ag<1e8f))) bad++;
  }
  for (int o=32;o;o>>=1) bad += __shfl_down(bad,o);
  __shared__ int sb;
  if (threadIdx.x==0) sb=0;
  __syncthreads();
  if ((threadIdx.x&63)==0) atomicAdd(&sb,bad);
  __syncthreads();
  if (threadIdx.x==0) *p.flag = (sb < 512) ? 1 : 0;
}

// ---- merged: y<2 -> column stats (nt flat stream); y>=2 -> edge binning ----
__global__ __launch_bounds__(256) void k_statsbin(P p){
  __shared__ unsigned smem[6664];
  int t = threadIdx.x;
  if (blockIdx.y < 2){
    int f = blockIdx.y;
    int isbf = *p.flag;
    if (!isbf){
      const float4* xf = (const float4*)p.x[f];
      const long NF4 = (long)N_NODES*32;
      const long G = (long)STB*256;
      long i0 = (long)blockIdx.x*256 + t;
      float s0=0,s1=0,s2=0,s3=0,q0=0,q1=0,q2=0,q3=0;
      for (long i=i0; i<NF4; i+=G){
        float4 v = ldnt(xf + i);
        s0+=v.x; q0+=v.x*v.x; s1+=v.y; q1+=v.y*v.y;
        s2+=v.z; q2+=v.z*v.z; s3+=v.w; q3+=v.w*v.w;
      }
      s0 += __shfl_xor(s0,32); q0 += __shfl_xor(q0,32);
      s1 += __shfl_xor(s1,32); q1 += __shfl_xor(q1,32);
      s2 += __shfl_xor(s2,32); q2 += __shfl_xor(q2,32);
      s3 += __shfl_xor(s3,32); q3 += __shfl_xor(q3,32);
      float* redf = (float*)smem;   // [wave][group][8]
      int wave=t>>6, lane=t&63;
      if (lane<32){
        float* d = redf + (wave*32+lane)*8;
        d[0]=s0; d[1]=s1; d[2]=s2; d[3]=s3; d[4]=q0; d[5]=q1; d[6]=q2; d[7]=q3;
      }
      __syncthreads();
      if (t < 128){
        int g = t>>2, k = t&3;
        float a = redf[(0*32+g)*8+k]+redf[(1*32+g)*8+k]+redf[(2*32+g)*8+k]+redf[(3*32+g)*8+k];
        float aq= redf[(0*32+g)*8+4+k]+redf[(1*32+g)*8+4+k]+redf[(2*32+g)*8+4+k]+redf[(3*32+g)*8+4+k];
        atomicAdd(&p.stats[f*256 + t], a);
        atomicAdd(&p.stats[f*256 + 128 + t], aq);
      }
      return;
    }
    // bf16 fallback: row pattern
    const void* x = p.x[f];
    int cb = t & 15, rg = t >> 4;
    int rpb = (N_NODES + STB - 1)/STB;
    int r0 = blockIdx.x*rpb;
    int r1 = r0 + rpb; if (r1 > N_NODES) r1 = N_NODES;
    float s[8], q[8];
    #pragma unroll
    for (int j=0;j<8;j++){ s[j]=0.f; q[j]=0.f; }
    for (int r = r0 + rg; r < r1; r += 16){
      F8 xv = load8(x, (long)r*DIM + cb*8, 1);
      #pragma unroll
      for (int j=0;j<8;j++){ s[j]+=xv.v[j]; q[j]+=xv.v[j]*xv.v[j]; }
    }
    float* red = (float*)smem;               // stride 9
    #pragma unroll
    for (int j=0;j<8;j++) red[t*9+j]=s[j];
    __syncthreads();
    if (t < 128){
      int cb2 = t>>3, j = t&7;
      float a=0.f;
      for (int g=0; g<16; g++) a += red[(g*16+cb2)*9 + j];
      atomicAdd(&p.stats[f*256 + cb2*8 + j], a);
    }
    __syncthreads();
    #pragma unroll
    for (int j=0;j<8;j++) red[t*9+j]=q[j];
    __syncthreads();
    if (t < 128){
      int cb2 = t>>3, j = t&7;
      float a=0.f;
      for (int g=0; g<16; g++) a += red[(g*16+cb2)*9 + j];
      atomicAdd(&p.stats[f*256 + 128 + cb2*8 + j], a);
    }
    return;
  }
  // ---- bin part ----
  int b = blockIdx.x, f = blockIdx.y - 2;
  if (b >= PB) return;
  unsigned* stage1 = smem;          // 3125
  unsigned* stage2 = smem + 3125;   // 3125
  unsigned* histS  = smem + 6250;   // 98
  unsigned* histD  = smem + 6348;   // 40
  unsigned* startS = smem + 6388;   // 98
  unsigned* startD = smem + 6486;   // 40
  unsigned* gbaseS = smem + 6526;   // 98
  unsigned* gbaseD = smem + 6624;   // 40
  const int* ei = p.ei[f];
  if (t < NBS) histS[t]=0;
  if (t < NBD) histD[t]=0;
  __syncthreads();
  int e0 = b*CHUNK;
  for (int i=t; i<CHUNK; i+=256){
    int src = ei[e0+i], dst = ei[N_EDGE+e0+i];
    unsigned nbs = (unsigned)src >> 10;
    stage1[i] = ((unsigned)src & 1023u) | ((unsigned)dst<<10) | (nbs<<25);
    atomicAdd(&histS[nbs], 1u);
    atomicAdd(&histD[(unsigned)dst>>9], 1u);
  }
  __syncthreads();
  if (t==0){ unsigned r=0; for (int k=0;k<NBS;k++){ startS[k]=r; r+=histS[k]; } }
  if (t==1){ unsigned r=0; for (int k=0;k<NBD;k++){ startD[k]=r; r+=histD[k]; } }
  __syncthreads();
  if (t < NBS) gbaseS[t] = atomicAdd(&p.curS[f*NBS+t], histS[t]);
  if (t >= 128 && t < 128+NBD) gbaseD[t-128] = atomicAdd(&p.curD[f*NBD+(t-128)], histD[t-128]);
  __syncthreads();
  if (t < NBS) histS[t]=0;
  __syncthreads();
  for (int i=t; i<CHUNK; i+=256){
    unsigned rec = stage1[i];
    unsigned nbs = rec>>25;
    unsigned r = atomicAdd(&histS[nbs],1u);
    stage2[startS[nbs]+r] = rec;
  }
  __syncthreads();
  for (int i=t; i<CHUNK; i+=256){
    unsigned rec = stage2[i];
    unsigned nbs = rec>>25;
    unsigned g = gbaseS[nbs] + (i - startS[nbs]);
    if (g < CAP_S) p.recS[((long)f*NBS+nbs)*CAP_S + g] = rec & 0x01FFFFFFu;
  }
  __syncthreads();
  if (t < NBD) histD[t]=0;
  __syncthreads();
  for (int i=t; i<CHUNK; i+=256){
    unsigned rec = stage1[i];
    unsigned dst = (rec>>10)&0x7FFFu;
    unsigned src = (rec>>25)*1024u + (rec&1023u);
    unsigned nbd = dst>>9;
    unsigned rd = (dst&511u) | (src<<9) | (nbd<<26);
    unsigned r = atomicAdd(&histD[nbd],1u);
    stage2[startD[nbd]+r] = rd;
  }
  __syncthreads();
  for (int i=t; i<CHUNK; i+=256){
    unsigned rd = stage2[i];
    unsigned nbd = rd>>26;
    unsigned g = gbaseD[nbd] + (i - startD[nbd]);
    if (g < CAP_D) p.recD[((long)f*NBD+nbd)*CAP_D + g] = rd & 0x03FFFFFFu;
  }
}

// ---- tiny prep ----
__global__ void k_prep(P p){
  __shared__ float csh[2][128];
  int t = threadIdx.x;
  int isbf = *p.flag;
  int f = t>>7, d = t&127;
  float sum = p.stats[f*256+d], sq = p.stats[f*256+128+d];
  float mean = sum * (1.0f/N_NODES);
  float ms = ldf(p.gms[f], d, isbf);
  float gw = ldf(p.gw[f],  d, isbf);
  float gb = ldf(p.gb[f],  d, isbf);
  float var = sq*(1.0f/N_NODES) - (2.0f*ms - ms*ms)*mean*mean;
  float av = gw / sqrtf(var + 1e-5f);
  p.a[f*128+d] = av;
  csh[f][d] = gb - av*ms*mean;
  if (isbf) ((unsigned short*)p.out)[256 + f*128 + d] = f2bf(mean);
  else      ((float*)p.out)[256 + f*128 + d] = mean;
  #pragma unroll
  for (int h=0; h<4; h++){
    float w1=0.f, w2=0.f;
    for (int o=0;o<32;o++){
      float Wv = ldf(p.W[f], d*DIM + h*32 + o, isbf);
      w1 += Wv * ldf(p.att[f], h*64+o,    isbf);
      w2 += Wv * ldf(p.att[f], h*64+32+o, isbf);
    }
    p.v[f*512 + d*4 + h] = av*w1;
    p.u[f*512 + d*4 + h] = w2;
  }
  __syncthreads();
  float acc = 0.f;
  for (int dd=0; dd<128; dd++) acc += csh[f][dd]*ldf(p.W[f], dd*DIM+d, isbf);
  p.cw[f*128+d] = acc;
  __syncthreads();
  if (t < 8){
    int ff=t>>2, h=t&3;
    float s2=0.f;
    for (int o=0;o<32;o++) s2 += p.cw[ff*128+h*32+o]*ldf(p.att[ff], h*64+o, isbf);
    p.cst[ff*4+h]=s2;
  }
}

// ---- logits -> bf16 tables (nt flat stream for f32) ----
__global__ __launch_bounds__(256) void k_logits(P p){
  int job = blockIdx.y;
  int f = job & 1;
  bool node = job < 2;
  int isbf = *p.flag;
  const void* X = node ? p.x[f] : p.ea[f];
  const float* coef = node ? (p.v + f*512) : (p.u + f*512);
  ushort4* outb = node ? ((ushort4*)p.lnb + (long)f*N_NODES)
                       : ((ushort4*)p.lhb + (long)f*N_HE);
  int R = node ? N_NODES : N_HE;
  int t = threadIdx.x;
  float4 cst4 = make_float4(0.f,0.f,0.f,0.f);
  if (node) cst4 = *(const float4*)(p.cst + f*4);
  if (!isbf){
    int c = t & 31;
    float cf[4][4];
    #pragma unroll
    for (int k=0;k<4;k++)
      #pragma unroll
      for (int h=0;h<4;h++)
        cf[k][h] = coef[(c*4+k)*4+h];
    const float4* Xf = (const float4*)X;
    const long NF4 = (long)R*32;
    const long G = (long)STB*256;
    long i0 = (long)blockIdx.x*256 + t;
    for (long i=i0; i<NF4; i+=G){
      float4 v = ldnt(Xf + i);
      float p0 = v.x*cf[0][0]+v.y*cf[1][0]+v.z*cf[2][0]+v.w*cf[3][0];
      float p1 = v.x*cf[0][1]+v.y*cf[1][1]+v.z*cf[2][1]+v.w*cf[3][1];
      float p2 = v.x*cf[0][2]+v.y*cf[1][2]+v.z*cf[2][2]+v.w*cf[3][2];
      float p3 = v.x*cf[0][3]+v.y*cf[1][3]+v.z*cf[2][3]+v.w*cf[3][3];
      #pragma unroll
      for (int m=1;m<32;m<<=1){
        p0 += __shfl_xor(p0,m);
        p1 += __shfl_xor(p1,m);
        p2 += __shfl_xor(p2,m);
        p3 += __shfl_xor(p3,m);
      }
      if (c==0){
        long row = i >> 5;
        ushort4 o;
        o.x = f2bf(p0 + cst4.x);
        o.y = f2bf(p1 + cst4.y);
        o.z = f2bf(p2 + cst4.z);
        o.w = f2bf(p3 + cst4.w);
        outb[row] = o;
      }
    }
    return;
  }
  // bf16 fallback: row pattern
  int cb = t & 15, rl = t >> 4;
  float cf[8][4];
  #pragma unroll
  for (int j=0;j<8;j++)
    #pragma unroll
    for (int h=0;h<4;h++)
      cf[j][h] = coef[(cb*8+j)*4+h];
  int rpb = (R + STB - 1)/STB;
  int r0 = blockIdx.x*rpb;
  int r1 = r0+rpb; if (r1>R) r1=R;
  for (int r = r0 + rl; r < r1; r += 16){
    F8 xv = load8(X, (long)r*DIM + cb*8, 1);
    float a0=0.f,a1=0.f,a2=0.f,a3=0.f;
    #pragma unroll
    for (int j=0;j<8;j++){
      a0 += xv.v[j]*cf[j][0];
      a1 += xv.v[j]*cf[j][1];
      a2 += xv.v[j]*cf[j][2];
      a3 += xv.v[j]*cf[j][3];
    }
    #pragma unroll
    for (int m=1;m<16;m<<=1){
      a0 += __shfl_xor(a0,m);
      a1 += __shfl_xor(a1,m);
      a2 += __shfl_xor(a2,m);
      a3 += __shfl_xor(a3,m);
    }
    if (cb==0){
      ushort4 o;
      o.x = f2bf(a0 + cst4.x);
      o.y = f2bf(a1 + cst4.y);
      o.z = f2bf(a2 + cst4.z);
      o.w = f2bf(a3 + cst4.w);
      outb[r] = o;
    }
  }
}

// ---- s accumulation per dst bucket (8KB LDS), from recD ----
__global__ __launch_bounds__(256) void k_sD(P p){
  __shared__ float sh[512*4];
  int nbd = blockIdx.x, sub = blockIdx.y, f = blockIdx.z, t = threadIdx.x;
  for (int i=t; i<512; i+=256) *(float4*)(sh+i*4) = make_float4(0,0,0,0);
  __syncthreads();
  unsigned cnt = p.curD[f*NBD+nbd]; if (cnt > CAP_D) cnt = CAP_D;
  int lo = (int)((long)cnt*sub/SUBD), hi = (int)((long)cnt*(sub+1)/SUBD);
  const unsigned* base = p.recD + ((long)f*NBD+nbd)*CAP_D;
  const ushort4* lnb = (const ushort4*)p.lnb + (long)f*N_NODES;
  const ushort4* lhb = (const ushort4*)p.lhb + (long)f*N_HE;
  for (int i=lo+t; i<hi; i+=256){
    unsigned rd = base[i];
    unsigned dstRel = rd & 511u;
    unsigned src = rd >> 9;
    ushort4 A = lnb[src];
    ushort4 B = lhb[nbd*512 + dstRel];
    float z0=b2f(A.x)+b2f(B.x), z1=b2f(A.y)+b2f(B.y);
    float z2=b2f(A.z)+b2f(B.z), z3=b2f(A.w)+b2f(B.w);
    z0 = z0>=0.f? z0 : 0.2f*z0;  z1 = z1>=0.f? z1 : 0.2f*z1;
    z2 = z2>=0.f? z2 : 0.2f*z2;  z3 = z3>=0.f? z3 : 0.2f*z3;
    float* tgt = sh + dstRel*4;
    atomicAdd(tgt+0, __expf(z0));
    atomicAdd(tgt+1, __expf(z1));
    atomicAdd(tgt+2, __expf(z2));
    atomicAdd(tgt+3, __expf(z3));
  }
  __syncthreads();
  float* out = p.sPart + (((long)f*NBD+nbd)*SUBD + sub)*2048;
  for (int i=t; i<512; i+=256) *(float4*)(out+i*4) = *(float4*)(sh+i*4);
}

// ---- reduce s partials -> hsv table {lhb 4xbf16, sinv 4xbf16} ----
__global__ void k_sred(P p){
  int idx = blockIdx.x*256 + threadIdx.x;
  if (idx >= 2*N_HE) return;
  int f = idx / N_HE, he = idx % N_HE;
  int nbd = he>>9, rel = he&511;
  float4 acc = make_float4(0,0,0,0);
  const float* base = p.sPart + ((long)(f*NBD+nbd)*SUBD)*2048 + rel*4;
  #pragma unroll
  for (int s=0;s<SUBD;s++){
    float4 v = ldnt((const float4*)(base + (long)s*2048));
    acc.x+=v.x; acc.y+=v.y; acc.z+=v.z; acc.w+=v.w;
  }
  ushort4 lh = ((const ushort4*)p.lhb)[(long)f*N_HE + he];
  uint4 o;
  o.x = (unsigned)lh.x | ((unsigned)lh.y<<16);
  o.y = (unsigned)lh.z | ((unsigned)lh.w<<16);
  o.z = (unsigned)f2bf(1.0f/(acc.x+1e-16f)) | ((unsigned)f2bf(1.0f/(acc.y+1e-16f))<<16);
  o.w = (unsigned)f2bf(1.0f/(acc.z+1e-16f)) | ((unsigned)f2bf(1.0f/(acc.w+1e-16f))<<16);
  ((uint4*)p.hsv)[(long)f*N_HE + he] = o;
}

// ---- Wn accumulation per src bucket (16KB LDS), from recS ----
__global__ __launch_bounds__(256) void k_wnD(P p){
  __shared__ float sh[1024*4];
  int nbs = blockIdx.x, sub = blockIdx.y, f = blockIdx.z, t = threadIdx.x;
  for (int i=t; i<1024; i+=256) *(float4*)(sh+i*4) = make_float4(0,0,0,0);
  __syncthreads();
  unsigned cnt = p.curS[f*NBS+nbs]; if (cnt > CAP_S) cnt = CAP_S;
  int lo = (int)((long)cnt*sub/SUBS), hi = (int)((long)cnt*(sub+1)/SUBS);
  const unsigned* base = p.recS + ((long)f*NBS+nbs)*CAP_S;
  const ushort4* lnb = (const ushort4*)p.lnb + (long)f*N_NODES;
  const uint4* hsv = (const uint4*)p.hsv + (long)f*N_HE;
  for (int i=lo+t; i<hi; i+=256){
    unsigned rec = base[i];
    unsigned srcRel = rec & 1023u;
    unsigned dst = rec >> 10;
    ushort4 A = lnb[nbs*1024 + srcRel];
    uint4 H = hsv[dst];
    float z0=b2f(A.x)+b2f((unsigned short)(H.x&0xFFFF)), z1=b2f(A.y)+b2f((unsigned short)(H.x>>16));
    float z2=b2f(A.z)+b2f((unsigned short)(H.y&0xFFFF)), z3=b2f(A.w)+b2f((unsigned short)(H.y>>16));
    z0 = z0>=0.f? z0 : 0.2f*z0;  z1 = z1>=0.f? z1 : 0.2f*z1;
    z2 = z2>=0.f? z2 : 0.2f*z2;  z3 = z3>=0.f? z3 : 0.2f*z3;
    float si0=b2f((unsigned short)(H.z&0xFFFF)), si1=b2f((unsigned short)(H.z>>16));
    float si2=b2f((unsigned short)(H.w&0xFFFF)), si3=b2f((unsigned short)(H.w>>16));
    float* tgt = sh + srcRel*4;
    atomicAdd(tgt+0, __expf(z0)*si0);
    atomicAdd(tgt+1, __expf(z1)*si1);
    atomicAdd(tgt+2, __expf(z2)*si2);
    atomicAdd(tgt+3, __expf(z3)*si3);
  }
  __syncthreads();
  float* out = p.wnPart + (((long)f*NBS+nbs)*SUBS + sub)*4096;
  for (int i=t; i<1024; i+=256) *(float4*)(out+i*4) = *(float4*)(sh+i*4);
}

// ---- dense pass: G[h,d] = sum_n wn[n,h]*x[n,d]; SW[h] = sum_n wn[n,h] ----
__global__ __launch_bounds__(256) void k_gpass(P p){
  int f = blockIdx.y;
  int isbf = *p.flag;
  const void* xs = p.x[f];
  int cb = threadIdx.x & 15, rg = threadIdx.x >> 4;
  float acc[8][4]; float sw[4]={0.f,0.f,0.f,0.f};
  #pragma unroll
  for (int j=0;j<8;j++)
    #pragma unroll
    for (int h=0;h<4;h++) acc[j][h]=0.f;
  int rpb = (N_NODES + GPB - 1)/GPB;
  int r0 = blockIdx.x*rpb;
  int r1 = r0+rpb; if (r1>N_NODES) r1=N_NODES;
  for (int r = r0 + rg; r < r1; r += 16){
    int nbs = r>>10, rel = r&1023;
    const float* wb = p.wnPart + ((long)(f*NBS+nbs)*SUBS)*4096 + rel*4;
    float4 wv = make_float4(0,0,0,0);
    #pragma unroll
    for (int s=0;s<SUBS;s++){
      float4 v = ldnt((const float4*)(wb + (long)s*4096));
      wv.x+=v.x; wv.y+=v.y; wv.z+=v.z; wv.w+=v.w;
    }
    F8 xv = load8nt(xs, (long)r*DIM + cb*8, isbf);
    float wvv[4]={wv.x,wv.y,wv.z,wv.w};
    #pragma unroll
    for (int j=0;j<8;j++)
      #pragma unroll
      for (int h=0;h<4;h++) acc[j][h] += xv.v[j]*wvv[h];
    if (cb==0){ sw[0]+=wv.x; sw[1]+=wv.y; sw[2]+=wv.z; sw[3]+=wv.w; }
  }
  __shared__ float red[16][16][33];
  __shared__ float red2[16][4];
  #pragma unroll
  for (int j=0;j<8;j++)
    #pragma unroll
    for (int h=0;h<4;h++) red[rg][cb][j*4+h]=acc[j][h];
  if (cb==0){ red2[rg][0]=sw[0]; red2[rg][1]=sw[1]; red2[rg][2]=sw[2]; red2[rg][3]=sw[3]; }
  __syncthreads();
  float* gp = p.gpart + ((long)f*GPB + blockIdx.x)*520;
  for (int idx=threadIdx.x; idx<512; idx+=256){
    int d=idx>>2, h=idx&3, cb2=d>>3, j=d&7;
    float a=0.f;
    #pragma unroll
    for (int g=0; g<16; g++) a += red[g][cb2][j*4+h];
    gp[idx] = a;
  }
  if (threadIdx.x<4){
    float a=0.f;
    for (int g=0;g<16;g++) a+=red2[g][threadIdx.x];
    gp[512+threadIdx.x] = a;
  }
}

// ---- gredA + (last block) final epilogue (64 blocks: fence cost OK) ----
__global__ void k_gredfin(P p){
  int g = blockIdx.x, f = blockIdx.y;
  int slabs = GPB/GGRP;
  const float* base = p.gpart + ((long)f*GPB + (long)g*slabs)*520;
  for (int i=threadIdx.x; i<516; i+=256){
    float acc = 0.f;
    for (int s=0;s<slabs;s++) acc += base[(long)s*520 + i];
    p.gpart2[((long)f*GGRP + g)*520 + i] = acc;
  }
  __syncthreads();
  __threadfence();
  __shared__ unsigned isLast;
  if (threadIdx.x==0){
    unsigned old = atomicAdd(p.done, 1u);
    isLast = (old == (unsigned)(GGRP*2 - 1)) ? 1u : 0u;
  }
  __syncthreads();
  if (!isLast) return;
  __threadfence();
  __shared__ float Gs[2][512];
  __shared__ float SWs[2][4];
  int t = threadIdx.x;
  for (int idx=t; idx<2*516; idx+=256){
    int ff = idx/516, i = idx%516;
    const float* b = p.gpart2 + (long)ff*GGRP*520 + i;
    float acc = 0.f;
    for (int gg=0; gg<GGRP; gg++) acc += b[(long)gg*520];
    if (i < 512) Gs[ff][i] = acc; else SWs[ff][i-512] = acc;
  }
  __syncthreads();
  int isbf = *p.flag;
  int ff = t>>7, k = t&127, h = k>>5;
  float acc = 0.f;
  for (int d=0; d<128; d++)
    acc += Gs[ff][d*4+h] * p.a[ff*128+d] * ldf(p.W[ff], d*DIM+k, isbf);
  acc += p.cw[ff*128+k]*SWs[ff][h];
  float o = acc*(1.0f/N_HE) + ldf(p.bias[ff], k, isbf);
  if (isbf) ((unsigned short*)p.out)[ff*128+k] = f2bf(o);
  else      ((float*)p.out)[ff*128+k] = o;
}

extern "C" void kernel_launch(void* const* d_in, const int* in_sizes, int n_in,
                              void* d_out, int out_size, void* d_ws, size_t ws_size,
                              hipStream_t stream){
  P p;
  p.x[0]=d_in[0];  p.ea[0]=d_in[1];  p.x[1]=d_in[2];  p.ea[1]=d_in[3];
  p.ei[0]=(const int*)d_in[4];  p.ei[1]=(const int*)d_in[5];
  p.gw[0]=d_in[6];  p.gb[0]=d_in[7];  p.gms[0]=d_in[8];
  p.W[0]=d_in[9];   p.att[0]=d_in[10]; p.bias[0]=d_in[11];
  p.gw[1]=d_in[12]; p.gb[1]=d_in[13]; p.gms[1]=d_in[14];
  p.W[1]=d_in[15];  p.att[1]=d_in[16]; p.bias[1]=d_in[17];

  float* w = (float*)d_ws;
  size_t off = 0;
  p.stats = w+off; off += 512;                      // zeroed by k_detect (880 floats)
  p.flag  = (int*)(w+off); off += 8;
  p.curS  = (unsigned*)(w+off); off += 256;         // 2*98 used
  p.curD  = (unsigned*)(w+off); off += 96;          // 2*40 used
  p.done  = (unsigned*)(w+off); off += 8;           // zero range = 880
  p.a     = w+off; off += 256;
  p.cw    = w+off; off += 256;
  p.v     = w+off; off += 1024;
  p.u     = w+off; off += 1024;
  p.cst   = w+off; off += 16;
  p.lnb   = (unsigned short*)(w+off); off += (size_t)2*N_NODES*2;   // 4 bf16/node
  p.lhb   = (unsigned short*)(w+off); off += (size_t)2*N_HE*2;
  p.hsv   = (unsigned short*)(w+off); off += (size_t)2*N_HE*4;      // 8 bf16/he
  p.recS  = (unsigned*)(w+off); off += (size_t)2*NBS*CAP_S;
  p.recD  = (unsigned*)(w+off); off += (size_t)2*NBD*CAP_D;
  p.sPart = w+off; off += (size_t)2*NBD*SUBD*2048;
  p.wnPart= w+off; off += (size_t)2*NBS*SUBS*4096;
  p.gpart = w+off; off += (size_t)2*GPB*520;
  p.gpart2= w+off; off += (size_t)2*GGRP*520;
  p.out   = d_out;

  k_detect  <<<dim3(1),          dim3(256), 0, stream>>>(p);
  k_statsbin<<<dim3(STB,4),      dim3(256), 0, stream>>>(p);
  k_prep    <<<dim3(1),          dim3(256), 0, stream>>>(p);
  k_logits  <<<dim3(STB,4),      dim3(256), 0, stream>>>(p);
  k_sD      <<<dim3(NBD,SUBD,2), dim3(256), 0, stream>>>(p);
  k_sred    <<<dim3((2*N_HE+255)/256), dim3(256), 0, stream>>>(p);
  k_wnD     <<<dim3(NBS,SUBS,2), dim3(256), 0, stream>>>(p);
  k_gpass   <<<dim3(GPB,2),      dim3(256), 0, stream>>>(p);
  k_gredfin <<<dim3(GGRP,2),     dim3(256), 0, stream>>>(p);
}

// Round 16
// 226.906 us; speedup vs baseline: 1.1508x; 1.1508x over previous
//
#include <hip/hip_runtime.h>

#define N_NODES 100000
#define N_HE    20000
#define N_EDGE  800000
#define DIM     128
#define NBS     98        // src buckets of 1024 nodes
#define NBD     40        // dst buckets of 512 hyperedges
#define CAP_S   9600
#define CAP_D   22500
#define SUBS    8
#define SUBD    16
#define PB      256       // bin blocks per frame
#define CHUNK   3125      // 256*3125 = 800000 exact
#define STB     400       // stats/logits blocks per frame/job
#define GPB     512       // gpass blocks per frame
#define GGRP    32

struct P {
  const void* x[2]; const void* ea[2]; const int* ei[2];
  const void* gw[2]; const void* gb[2]; const void* gms[2];
  const void* W[2]; const void* att[2]; const void* bias[2];
  float *stats, *a, *cw, *v, *u, *cst, *sPart, *wnPart, *gpart, *gpart2;
  unsigned *curS, *curD, *done, *recS, *recD;
  unsigned short *lnb, *lhb, *hsv;
  int* flag; void* out;
};

// ---- helpers ----
__device__ __forceinline__ float ldf(const void* p, int i, int isbf){
  if (isbf){ unsigned short h = ((const unsigned short*)p)[i]; return __uint_as_float(((unsigned)h)<<16); }
  return ((const float*)p)[i];
}
__device__ __forceinline__ float b2f(unsigned short h){
  return __uint_as_float(((unsigned)h)<<16);
}
struct F8 { float v[8]; };
__device__ __forceinline__ F8 load8(const void* p, long idx, int isbf){
  F8 r;
  if (isbf){
    uint4 q = *(const uint4*)((const unsigned short*)p + idx);
    r.v[0]=__uint_as_float(q.x<<16); r.v[1]=__uint_as_float(q.x&0xFFFF0000u);
    r.v[2]=__uint_as_float(q.y<<16); r.v[3]=__uint_as_float(q.y&0xFFFF0000u);
    r.v[4]=__uint_as_float(q.z<<16); r.v[5]=__uint_as_float(q.z&0xFFFF0000u);
    r.v[6]=__uint_as_float(q.w<<16); r.v[7]=__uint_as_float(q.w&0xFFFF0000u);
  } else {
    const float4* q = (const float4*)((const float*)p + idx);
    float4 A=q[0], B=q[1];
    r.v[0]=A.x;r.v[1]=A.y;r.v[2]=A.z;r.v[3]=A.w;
    r.v[4]=B.x;r.v[5]=B.y;r.v[6]=B.z;r.v[7]=B.w;
  }
  return r;
}
__device__ __forceinline__ unsigned short f2bf(float f){
  unsigned u = __float_as_uint(f);
  return (unsigned short)((u + 0x7FFFu + ((u>>16)&1u)) >> 16);   // RNE
}

// ---- dtype detection + zero stats/flag/cursors/done ----
__global__ void k_detect(P p){
  for (int i=threadIdx.x; i<880; i+=256) p.stats[i]=0.f;
  const unsigned* w = (const unsigned*)p.x[0];
  int bad = 0;
  for (int i = threadIdx.x; i < 4096; i += 256){
    float g = __uint_as_float(w[i]<<16);
    float ag = fabsf(g);
    if (!(ag==0.0f || (ag>1e-8f && ag<1e8f))) bad++;
  }
  for (int o=32;o;o>>=1) bad += __shfl_down(bad,o);
  __shared__ int sb;
  if (threadIdx.x==0) sb=0;
  __syncthreads();
  if ((threadIdx.x&63)==0) atomicAdd(&sb,bad);
  __syncthreads();
  if (threadIdx.x==0) *p.flag = (sb < 512) ? 1 : 0;
}

// ---- merged: y<2 -> column stats (pure read); y>=2 -> edge binning ----
__global__ __launch_bounds__(256) void k_statsbin(P p){
  __shared__ unsigned smem[6664];   // overlay: stats red (2304 f) | bin tables
  int t = threadIdx.x;
  if (blockIdx.y < 2){
    int f = blockIdx.y;
    const void* x = p.x[f];
    int isbf = *p.flag;
    int cb = t & 15, rg = t >> 4;
    int rpb = (N_NODES + STB - 1)/STB;
    int r0 = blockIdx.x*rpb;
    int r1 = r0 + rpb; if (r1 > N_NODES) r1 = N_NODES;
    float s[8], q[8];
    #pragma unroll
    for (int j=0;j<8;j++){ s[j]=0.f; q[j]=0.f; }
    for (int r = r0 + rg; r < r1; r += 16){
      F8 xv = load8(x, (long)r*DIM + cb*8, isbf);
      #pragma unroll
      for (int j=0;j<8;j++){ s[j]+=xv.v[j]; q[j]+=xv.v[j]*xv.v[j]; }
    }
    float* red = (float*)smem;               // stride 9
    #pragma unroll
    for (int j=0;j<8;j++) red[t*9+j]=s[j];
    __syncthreads();
    if (t < 128){
      int cb2 = t>>3, j = t&7;
      float a=0.f;
      for (int g=0; g<16; g++) a += red[(g*16+cb2)*9 + j];
      atomicAdd(&p.stats[f*256 + cb2*8 + j], a);
    }
    __syncthreads();
    #pragma unroll
    for (int j=0;j<8;j++) red[t*9+j]=q[j];
    __syncthreads();
    if (t < 128){
      int cb2 = t>>3, j = t&7;
      float a=0.f;
      for (int g=0; g<16; g++) a += red[(g*16+cb2)*9 + j];
      atomicAdd(&p.stats[f*256 + 128 + cb2*8 + j], a);
    }
    return;
  }
  // ---- bin part ----
  int b = blockIdx.x, f = blockIdx.y - 2;
  if (b >= PB) return;
  unsigned* stage1 = smem;
  unsigned* stage2 = smem + 3125;
  unsigned* histS  = smem + 6250;   // 98
  unsigned* histD  = smem + 6348;   // 40
  unsigned* startS = smem + 6388;   // 98
  unsigned* startD = smem + 6486;   // 40
  unsigned* gbaseS = smem + 6526;   // 98
  unsigned* gbaseD = smem + 6624;   // 40
  const int* ei = p.ei[f];
  if (t < NBS) histS[t]=0;
  if (t < NBD) histD[t]=0;
  __syncthreads();
  int e0 = b*CHUNK;
  for (int i=t; i<CHUNK; i+=256){
    int src = ei[e0+i], dst = ei[N_EDGE+e0+i];
    unsigned nbs = (unsigned)src >> 10;
    stage1[i] = ((unsigned)src & 1023u) | ((unsigned)dst<<10) | (nbs<<25);
    atomicAdd(&histS[nbs], 1u);
    atomicAdd(&histD[(unsigned)dst>>9], 1u);
  }
  __syncthreads();
  if (t==0){ unsigned r=0; for (int k=0;k<NBS;k++){ startS[k]=r; r+=histS[k]; } }
  if (t==1){ unsigned r=0; for (int k=0;k<NBD;k++){ startD[k]=r; r+=histD[k]; } }
  __syncthreads();
  if (t < NBS) gbaseS[t] = atomicAdd(&p.curS[f*NBS+t], histS[t]);
  if (t >= 128 && t < 128+NBD) gbaseD[t-128] = atomicAdd(&p.curD[f*NBD+(t-128)], histD[t-128]);
  __syncthreads();
  if (t < NBS) histS[t]=0;
  __syncthreads();
  for (int i=t; i<CHUNK; i+=256){
    unsigned rec = stage1[i];
    unsigned nbs = rec>>25;
    unsigned r = atomicAdd(&histS[nbs],1u);
    stage2[startS[nbs]+r] = rec;
  }
  __syncthreads();
  for (int i=t; i<CHUNK; i+=256){
    unsigned rec = stage2[i];
    unsigned nbs = rec>>25;
    unsigned g = gbaseS[nbs] + (i - startS[nbs]);
    if (g < CAP_S) p.recS[((long)f*NBS+nbs)*CAP_S + g] = rec & 0x01FFFFFFu;
  }
  __syncthreads();
  if (t < NBD) histD[t]=0;
  __syncthreads();
  for (int i=t; i<CHUNK; i+=256){
    unsigned rec = stage1[i];
    unsigned dst = (rec>>10)&0x7FFFu;
    unsigned src = (rec>>25)*1024u + (rec&1023u);
    unsigned nbd = dst>>9;
    unsigned rd = (dst&511u) | (src<<9) | (nbd<<26);
    unsigned r = atomicAdd(&histD[nbd],1u);
    stage2[startD[nbd]+r] = rd;
  }
  __syncthreads();
  for (int i=t; i<CHUNK; i+=256){
    unsigned rd = stage2[i];
    unsigned nbd = rd>>26;
    unsigned g = gbaseD[nbd] + (i - startD[nbd]);
    if (g < CAP_D) p.recD[((long)f*NBD+nbd)*CAP_D + g] = rd & 0x03FFFFFFu;
  }
}

// ---- tiny prep ----
__global__ void k_prep(P p){
  __shared__ float csh[2][128];
  int t = threadIdx.x;
  int isbf = *p.flag;
  int f = t>>7, d = t&127;
  float sum = p.stats[f*256+d], sq = p.stats[f*256+128+d];
  float mean = sum * (1.0f/N_NODES);
  float ms = ldf(p.gms[f], d, isbf);
  float gw = ldf(p.gw[f],  d, isbf);
  float gb = ldf(p.gb[f],  d, isbf);
  float var = sq*(1.0f/N_NODES) - (2.0f*ms - ms*ms)*mean*mean;
  float av = gw / sqrtf(var + 1e-5f);
  p.a[f*128+d] = av;
  csh[f][d] = gb - av*ms*mean;
  if (isbf) ((unsigned short*)p.out)[256 + f*128 + d] = f2bf(mean);
  else      ((float*)p.out)[256 + f*128 + d] = mean;
  #pragma unroll
  for (int h=0; h<4; h++){
    float w1=0.f, w2=0.f;
    for (int o=0;o<32;o++){
      float Wv = ldf(p.W[f], d*DIM + h*32 + o, isbf);
      w1 += Wv * ldf(p.att[f], h*64+o,    isbf);
      w2 += Wv * ldf(p.att[f], h*64+32+o, isbf);
    }
    p.v[f*512 + d*4 + h] = av*w1;
    p.u[f*512 + d*4 + h] = w2;
  }
  __syncthreads();
  float acc = 0.f;
  for (int dd=0; dd<128; dd++) acc += csh[f][dd]*ldf(p.W[f], dd*DIM+d, isbf);
  p.cw[f*128+d] = acc;
  __syncthreads();
  if (t < 8){
    int ff=t>>2, h=t&3;
    float s2=0.f;
    for (int o=0;o<32;o++) s2 += p.cw[ff*128+h*32+o]*ldf(p.att[ff], h*64+o, isbf);
    p.cst[ff*4+h]=s2;
  }
}

// ---- logits -> bf16 tables lnb / lhb (reads raw x / eattr) ----
__global__ __launch_bounds__(256) void k_logits(P p){
  int job = blockIdx.y;
  int f = job & 1;
  bool node = job < 2;
  int isbf = *p.flag;
  const void* X = node ? p.x[f] : p.ea[f];
  const float* coef = node ? (p.v + f*512) : (p.u + f*512);
  ushort4* outb = node ? ((ushort4*)p.lnb + (long)f*N_NODES)
                       : ((ushort4*)p.lhb + (long)f*N_HE);
  int R = node ? N_NODES : N_HE;
  int cb = threadIdx.x & 15, rl = threadIdx.x >> 4;
  float cf[8][4];
  #pragma unroll
  for (int j=0;j<8;j++)
    #pragma unroll
    for (int h=0;h<4;h++)
      cf[j][h] = coef[(cb*8+j)*4+h];
  float4 cst4 = make_float4(0.f,0.f,0.f,0.f);
  if (node) cst4 = *(const float4*)(p.cst + f*4);
  int rpb = (R + gridDim.x - 1)/gridDim.x;
  int r0 = blockIdx.x*rpb;
  int r1 = r0+rpb; if (r1>R) r1=R;
  for (int r = r0 + rl; r < r1; r += 16){
    F8 xv = load8(X, (long)r*DIM + cb*8, isbf);
    float a0=0.f,a1=0.f,a2=0.f,a3=0.f;
    #pragma unroll
    for (int j=0;j<8;j++){
      a0 += xv.v[j]*cf[j][0];
      a1 += xv.v[j]*cf[j][1];
      a2 += xv.v[j]*cf[j][2];
      a3 += xv.v[j]*cf[j][3];
    }
    #pragma unroll
    for (int m=1;m<16;m<<=1){
      a0 += __shfl_xor(a0,m);
      a1 += __shfl_xor(a1,m);
      a2 += __shfl_xor(a2,m);
      a3 += __shfl_xor(a3,m);
    }
    if (cb==0){
      ushort4 o;
      o.x = f2bf(a0 + cst4.x);
      o.y = f2bf(a1 + cst4.y);
      o.z = f2bf(a2 + cst4.z);
      o.w = f2bf(a3 + cst4.w);
      outb[r] = o;
    }
  }
}

// ---- s accumulation per dst bucket (8KB LDS), from recD ----
__global__ __launch_bounds__(256) void k_sD(P p){
  __shared__ float sh[512*4];
  int nbd = blockIdx.x, sub = blockIdx.y, f = blockIdx.z, t = threadIdx.x;
  for (int i=t; i<512; i+=256) *(float4*)(sh+i*4) = make_float4(0,0,0,0);
  __syncthreads();
  unsigned cnt = p.curD[f*NBD+nbd]; if (cnt > CAP_D) cnt = CAP_D;
  int lo = (int)((long)cnt*sub/SUBD), hi = (int)((long)cnt*(sub+1)/SUBD);
  const unsigned* base = p.recD + ((long)f*NBD+nbd)*CAP_D;
  const ushort4* lnb = (const ushort4*)p.lnb + (long)f*N_NODES;
  const ushort4* lhb = (const ushort4*)p.lhb + (long)f*N_HE;
  for (int i=lo+t; i<hi; i+=256){
    unsigned rd = base[i];
    unsigned dstRel = rd & 511u;
    unsigned src = rd >> 9;
    ushort4 A = lnb[src];
    ushort4 B = lhb[nbd*512 + dstRel];
    float z0=b2f(A.x)+b2f(B.x), z1=b2f(A.y)+b2f(B.y);
    float z2=b2f(A.z)+b2f(B.z), z3=b2f(A.w)+b2f(B.w);
    z0 = z0>=0.f? z0 : 0.2f*z0;  z1 = z1>=0.f? z1 : 0.2f*z1;
    z2 = z2>=0.f? z2 : 0.2f*z2;  z3 = z3>=0.f? z3 : 0.2f*z3;
    float* tgt = sh + dstRel*4;
    atomicAdd(tgt+0, __expf(z0));
    atomicAdd(tgt+1, __expf(z1));
    atomicAdd(tgt+2, __expf(z2));
    atomicAdd(tgt+3, __expf(z3));
  }
  __syncthreads();
  float* out = p.sPart + (((long)f*NBD+nbd)*SUBD + sub)*2048;
  for (int i=t; i<512; i+=256) *(float4*)(out+i*4) = *(float4*)(sh+i*4);
}

// ---- reduce s partials -> hsv table {lhb 4xbf16, sinv 4xbf16} ----
__global__ void k_sred(P p){
  int idx = blockIdx.x*256 + threadIdx.x;
  if (idx >= 2*N_HE) return;
  int f = idx / N_HE, he = idx % N_HE;
  int nbd = he>>9, rel = he&511;
  float4 acc = make_float4(0,0,0,0);
  const float* base = p.sPart + ((long)(f*NBD+nbd)*SUBD)*2048 + rel*4;
  #pragma unroll
  for (int s=0;s<SUBD;s++){
    float4 v = *(const float4*)(base + (long)s*2048);
    acc.x+=v.x; acc.y+=v.y; acc.z+=v.z; acc.w+=v.w;
  }
  ushort4 lh = ((const ushort4*)p.lhb)[(long)f*N_HE + he];
  uint4 o;
  o.x = (unsigned)lh.x | ((unsigned)lh.y<<16);
  o.y = (unsigned)lh.z | ((unsigned)lh.w<<16);
  o.z = (unsigned)f2bf(1.0f/(acc.x+1e-16f)) | ((unsigned)f2bf(1.0f/(acc.y+1e-16f))<<16);
  o.w = (unsigned)f2bf(1.0f/(acc.z+1e-16f)) | ((unsigned)f2bf(1.0f/(acc.w+1e-16f))<<16);
  ((uint4*)p.hsv)[(long)f*N_HE + he] = o;
}

// ---- Wn accumulation per src bucket (16KB LDS), from recS ----
__global__ __launch_bounds__(256) void k_wnD(P p){
  __shared__ float sh[1024*4];
  int nbs = blockIdx.x, sub = blockIdx.y, f = blockIdx.z, t = threadIdx.x;
  for (int i=t; i<1024; i+=256) *(float4*)(sh+i*4) = make_float4(0,0,0,0);
  __syncthreads();
  unsigned cnt = p.curS[f*NBS+nbs]; if (cnt > CAP_S) cnt = CAP_S;
  int lo = (int)((long)cnt*sub/SUBS), hi = (int)((long)cnt*(sub+1)/SUBS);
  const unsigned* base = p.recS + ((long)f*NBS+nbs)*CAP_S;
  const ushort4* lnb = (const ushort4*)p.lnb + (long)f*N_NODES;
  const uint4* hsv = (const uint4*)p.hsv + (long)f*N_HE;
  for (int i=lo+t; i<hi; i+=256){
    unsigned rec = base[i];
    unsigned srcRel = rec & 1023u;
    unsigned dst = rec >> 10;
    ushort4 A = lnb[nbs*1024 + srcRel];
    uint4 H = hsv[dst];
    float z0=b2f(A.x)+b2f((unsigned short)(H.x&0xFFFF)), z1=b2f(A.y)+b2f((unsigned short)(H.x>>16));
    float z2=b2f(A.z)+b2f((unsigned short)(H.y&0xFFFF)), z3=b2f(A.w)+b2f((unsigned short)(H.y>>16));
    z0 = z0>=0.f? z0 : 0.2f*z0;  z1 = z1>=0.f? z1 : 0.2f*z1;
    z2 = z2>=0.f? z2 : 0.2f*z2;  z3 = z3>=0.f? z3 : 0.2f*z3;
    float si0=b2f((unsigned short)(H.z&0xFFFF)), si1=b2f((unsigned short)(H.z>>16));
    float si2=b2f((unsigned short)(H.w&0xFFFF)), si3=b2f((unsigned short)(H.w>>16));
    float* tgt = sh + srcRel*4;
    atomicAdd(tgt+0, __expf(z0)*si0);
    atomicAdd(tgt+1, __expf(z1)*si1);
    atomicAdd(tgt+2, __expf(z2)*si2);
    atomicAdd(tgt+3, __expf(z3)*si3);
  }
  __syncthreads();
  float* out = p.wnPart + (((long)f*NBS+nbs)*SUBS + sub)*4096;
  for (int i=t; i<1024; i+=256) *(float4*)(out+i*4) = *(float4*)(sh+i*4);
}

// ---- dense pass: G[h,d] = sum_n wn[n,h]*x[n,d]; SW[h] = sum_n wn[n,h] ----
__global__ __launch_bounds__(256) void k_gpass(P p){
  int f = blockIdx.y;
  int isbf = *p.flag;
  const void* xs = p.x[f];
  int cb = threadIdx.x & 15, rg = threadIdx.x >> 4;
  float acc[8][4]; float sw[4]={0.f,0.f,0.f,0.f};
  #pragma unroll
  for (int j=0;j<8;j++)
    #pragma unroll
    for (int h=0;h<4;h++) acc[j][h]=0.f;
  int rpb = (N_NODES + GPB - 1)/GPB;
  int r0 = blockIdx.x*rpb;
  int r1 = r0+rpb; if (r1>N_NODES) r1=N_NODES;
  for (int r = r0 + rg; r < r1; r += 16){
    int nbs = r>>10, rel = r&1023;
    const float* wb = p.wnPart + ((long)(f*NBS+nbs)*SUBS)*4096 + rel*4;
    float4 wv = make_float4(0,0,0,0);
    #pragma unroll
    for (int s=0;s<SUBS;s++){
      float4 v = *(const float4*)(wb + (long)s*4096);
      wv.x+=v.x; wv.y+=v.y; wv.z+=v.z; wv.w+=v.w;
    }
    F8 xv = load8(xs, (long)r*DIM + cb*8, isbf);
    float wvv[4]={wv.x,wv.y,wv.z,wv.w};
    #pragma unroll
    for (int j=0;j<8;j++)
      #pragma unroll
      for (int h=0;h<4;h++) acc[j][h] += xv.v[j]*wvv[h];
    if (cb==0){ sw[0]+=wv.x; sw[1]+=wv.y; sw[2]+=wv.z; sw[3]+=wv.w; }
  }
  __shared__ float red[16][16][33];
  __shared__ float red2[16][4];
  #pragma unroll
  for (int j=0;j<8;j++)
    #pragma unroll
    for (int h=0;h<4;h++) red[rg][cb][j*4+h]=acc[j][h];
  if (cb==0){ red2[rg][0]=sw[0]; red2[rg][1]=sw[1]; red2[rg][2]=sw[2]; red2[rg][3]=sw[3]; }
  __syncthreads();
  float* gp = p.gpart + ((long)f*GPB + blockIdx.x)*520;
  for (int idx=threadIdx.x; idx<512; idx+=256){
    int d=idx>>2, h=idx&3, cb2=d>>3, j=d&7;
    float a=0.f;
    #pragma unroll
    for (int g=0; g<16; g++) a += red[g][cb2][j*4+h];
    gp[idx] = a;
  }
  if (threadIdx.x<4){
    float a=0.f;
    for (int g=0;g<16;g++) a+=red2[g][threadIdx.x];
    gp[512+threadIdx.x] = a;
  }
}

// ---- gredA + (last block) final epilogue ----
__global__ void k_gredfin(P p){
  int g = blockIdx.x, f = blockIdx.y;
  int slabs = GPB/GGRP;
  const float* base = p.gpart + ((long)f*GPB + (long)g*slabs)*520;
  for (int i=threadIdx.x; i<516; i+=256){
    float acc = 0.f;
    for (int s=0;s<slabs;s++) acc += base[(long)s*520 + i];
    p.gpart2[((long)f*GGRP + g)*520 + i] = acc;
  }
  __syncthreads();
  __threadfence();
  __shared__ unsigned isLast;
  if (threadIdx.x==0){
    unsigned old = atomicAdd(p.done, 1u);
    isLast = (old == (unsigned)(GGRP*2 - 1)) ? 1u : 0u;
  }
  __syncthreads();
  if (!isLast) return;
  __threadfence();
  __shared__ float Gs[2][512];
  __shared__ float SWs[2][4];
  int t = threadIdx.x;
  for (int idx=t; idx<2*516; idx+=256){
    int ff = idx/516, i = idx%516;
    const float* b = p.gpart2 + (long)ff*GGRP*520 + i;
    float acc = 0.f;
    for (int gg=0; gg<GGRP; gg++) acc += b[(long)gg*520];
    if (i < 512) Gs[ff][i] = acc; else SWs[ff][i-512] = acc;
  }
  __syncthreads();
  int isbf = *p.flag;
  int ff = t>>7, k = t&127, h = k>>5;
  float acc = 0.f;
  for (int d=0; d<128; d++)
    acc += Gs[ff][d*4+h] * p.a[ff*128+d] * ldf(p.W[ff], d*DIM+k, isbf);
  acc += p.cw[ff*128+k]*SWs[ff][h];
  float o = acc*(1.0f/N_HE) + ldf(p.bias[ff], k, isbf);
  if (isbf) ((unsigned short*)p.out)[ff*128+k] = f2bf(o);
  else      ((float*)p.out)[ff*128+k] = o;
}

extern "C" void kernel_launch(void* const* d_in, const int* in_sizes, int n_in,
                              void* d_out, int out_size, void* d_ws, size_t ws_size,
                              hipStream_t stream){
  P p;
  p.x[0]=d_in[0];  p.ea[0]=d_in[1];  p.x[1]=d_in[2];  p.ea[1]=d_in[3];
  p.ei[0]=(const int*)d_in[4];  p.ei[1]=(const int*)d_in[5];
  p.gw[0]=d_in[6];  p.gb[0]=d_in[7];  p.gms[0]=d_in[8];
  p.W[0]=d_in[9];   p.att[0]=d_in[10]; p.bias[0]=d_in[11];
  p.gw[1]=d_in[12]; p.gb[1]=d_in[13]; p.gms[1]=d_in[14];
  p.W[1]=d_in[15];  p.att[1]=d_in[16]; p.bias[1]=d_in[17];

  float* w = (float*)d_ws;
  size_t off = 0;
  p.stats = w+off; off += 512;                      // zeroed by k_detect (880 floats)
  p.flag  = (int*)(w+off); off += 8;
  p.curS  = (unsigned*)(w+off); off += 256;         // 2*98 used
  p.curD  = (unsigned*)(w+off); off += 96;          // 2*40 used
  p.done  = (unsigned*)(w+off); off += 8;           // zero range = 880
  p.a     = w+off; off += 256;
  p.cw    = w+off; off += 256;
  p.v     = w+off; off += 1024;
  p.u     = w+off; off += 1024;
  p.cst   = w+off; off += 16;
  p.lnb   = (unsigned short*)(w+off); off += (size_t)2*N_NODES*2;   // 4 bf16/node
  p.lhb   = (unsigned short*)(w+off); off += (size_t)2*N_HE*2;
  p.hsv   = (unsigned short*)(w+off); off += (size_t)2*N_HE*4;      // 8 bf16/he
  p.recS  = (unsigned*)(w+off); off += (size_t)2*NBS*CAP_S;
  p.recD  = (unsigned*)(w+off); off += (size_t)2*NBD*CAP_D;
  p.sPart = w+off; off += (size_t)2*NBD*SUBD*2048;
  p.wnPart= w+off; off += (size_t)2*NBS*SUBS*4096;
  p.gpart = w+off; off += (size_t)2*GPB*520;
  p.gpart2= w+off; off += (size_t)2*GGRP*520;
  p.out   = d_out;

  k_detect  <<<dim3(1),          dim3(256), 0, stream>>>(p);
  k_statsbin<<<dim3(STB,4),      dim3(256), 0, stream>>>(p);
  k_prep    <<<dim3(1),          dim3(256), 0, stream>>>(p);
  k_logits  <<<dim3(STB,4),      dim3(256), 0, stream>>>(p);
  k_sD      <<<dim3(NBD,SUBD,2), dim3(256), 0, stream>>>(p);
  k_sred    <<<dim3((2*N_HE+255)/256), dim3(256), 0, stream>>>(p);
  k_wnD     <<<dim3(NBS,SUBS,2), dim3(256), 0, stream>>>(p);
  k_gpass   <<<dim3(GPB,2),      dim3(256), 0, stream>>>(p);
  k_gredfin <<<dim3(GGRP,2),     dim3(256), 0, stream>>>(p);
}